// Round 13
// baseline (177.181 us; speedup 1.0000x reference)
//
#include <hip/hip_runtime.h>
#include <hip/hip_bf16.h>
#include <math.h>

#define B_DIM 8
#define C_DIM 32
#define N_DIM 4096
#define KSPLIT 2
#define KSL (N_DIM / KSPLIT)   // 2048 k per block
#define NCH (KSL / 32)         // 64 chunks

typedef short bf16x8 __attribute__((ext_vector_type(8)));   // 8 bf16 = 4 VGPRs
typedef float f32x4 __attribute__((ext_vector_type(4)));
typedef unsigned int uint4v __attribute__((ext_vector_type(4)));
typedef unsigned short ushort8 __attribute__((ext_vector_type(8)));

__device__ __forceinline__ ushort f2bf_rne(float f) {
  unsigned u = __float_as_uint(f);
  u += 0x7FFF + ((u >> 16) & 1);
  return (ushort)(u >> 16);
}

// Prep A: cadjs[b,n] = mean_c x[b,c,n] * log2(e)   (pre-scaled for exp2)
__global__ __launch_bounds__(256) void prep_cadj(const float* __restrict__ x,
                                                 float* __restrict__ cadjs) {
  int idx = blockIdx.x * 256 + threadIdx.x;   // 0 .. B*N-1
  int b = idx >> 12;
  int n = idx & (N_DIM - 1);
  const float* p = x + (size_t)b * C_DIM * N_DIM + n;
  float s = 0.f;
#pragma unroll
  for (int c = 0; c < C_DIM; ++c) s += p[(size_t)c * N_DIM];
  cadjs[idx] = s * (1.44269504f / C_DIM);
}

// Prep B: feabT tiled bf16: feabT[((b*128 + n/32)*32 + c)*32 + n%32]
__global__ __launch_bounds__(256) void prep_feab(const float* __restrict__ x,
                                                 ushort* __restrict__ feabT) {
  int idx = blockIdx.x * 256 + threadIdx.x;   // 0 .. 8*32*256-1
  int g = idx & 255;           // n-group of 16
  int c = (idx >> 8) & 31;
  int b = idx >> 13;
  int n0 = g * 16;
  const float* p = x + ((size_t)(b * C_DIM + c)) * N_DIM + n0;
  ushort* q = feabT + ((size_t)(b * (N_DIM / 32) + (n0 >> 5)) * C_DIM + c) * 32 + (n0 & 31);
  ushort8 v0, v1;
#pragma unroll
  for (int j = 0; j < 8; ++j) v0[j] = f2bf_rne(p[j]);
#pragma unroll
  for (int j = 0; j < 8; ++j) v1[j] = f2bf_rne(p[8 + j]);
  *(ushort8*)q = v0;
  *(ushort8*)(q + 8) = v1;
}

// Prep C: adjt = bf16(2*adj) transposed into k-major tiles.
// Tile (mg=m/16, kc=k/32): 1 KB, element (m%16)*32 + k%32.
// Thread t -> (m = idx & 4095, g = idx>>12 = k-group of 16): reads 16 rows of
// adj at column m (wave-coalesced: 64 consecutive m = 256 B per row), writes
// 32 B contiguous into the tile.
__global__ __launch_bounds__(256) void prep_adjT(const float* __restrict__ adj,
                                                 ushort* __restrict__ adjt) {
  const int idx = blockIdx.x * 256 + threadIdx.x;   // 0 .. 1048575
  const int m = idx & (N_DIM - 1);
  const int g = idx >> 12;          // 0..255
  const float* src = adj + (size_t)(g * 16) * N_DIM + m;
  ushort8 v0, v1;
#pragma unroll
  for (int i = 0; i < 8; ++i) v0[i] = f2bf_rne(2.0f * src[(size_t)i * N_DIM]);
#pragma unroll
  for (int i = 0; i < 8; ++i) v1[i] = f2bf_rne(2.0f * src[(size_t)(8 + i) * N_DIM]);
  ushort* dst = adjt + ((size_t)((m >> 4) * 128 + (g >> 1))) * 512 + (m & 15) * 32 + (g & 1) * 16;
  *(ushort8*)dst = v0;
  *(ushort8*)(dst + 8) = v1;
}

// Stage 1: block = 8 waves (512 thr); wave = ONE batch; 16 cols x K-half x all
// 8 batches. B-side comes from adjt tiles: ONE contiguous 16 B ushort8 load
// per lane per chunk, identical addresses across the 8 waves (L1-shared, adjt
// read once chip-wide). No LDS, no barriers, no scatter -- the compiler is
// free to pipeline chunks. bf16->f32 adj convert is 2 VALU ops per dword.
__global__ __launch_bounds__(512, 4) void gcn_stage1(
    const ushort* __restrict__ feabT, const ushort* __restrict__ adjt,
    const float* __restrict__ cadjs, float* __restrict__ part) {
  const int tid = threadIdx.x;
  const int lane = tid & 63;
  const int b = tid >> 6;           // wave id = batch
  const int quad = lane >> 4;
  const int l15 = lane & 15;
  const int colgrp = blockIdx.x;    // 0..255
  const int kh = blockIdx.y;        // 0..1
  const int col = colgrp * 16 + l15;
  const int kc0 = kh * (KSL / 32);

  const float cm = cadjs[b * N_DIM + col];
  const float* ckb = cadjs + (size_t)b * N_DIM + kh * KSL;
  const ushort* fb = feabT + ((size_t)b * (N_DIM / 32) + kc0) * (C_DIM * 32);
  const ushort* ab = adjt + ((size_t)(colgrp * 128 + kc0)) * 512 + l15 * 32 + quad * 8;

  f32x4 acc0 = {0.f, 0.f, 0.f, 0.f};   // channels 0-15
  f32x4 acc1 = {0.f, 0.f, 0.f, 0.f};   // channels 16-31

#pragma unroll 2
  for (int ch = 0; ch < NCH; ++ch) {
    const uint4v au = *(const uint4v*)(ab + (size_t)ch * 512);   // 8 bf16 of 2*adj

    const ushort* tile = fb + (size_t)ch * (C_DIM * 32);
    const bf16x8 fa0 = *(const bf16x8*)(tile + l15 * 32 + quad * 8);
    const bf16x8 fa1 = *(const bf16x8*)(tile + (16 + l15) * 32 + quad * 8);

    float ckv[8];
    *(f32x4*)&ckv[0] = *(const f32x4*)(ckb + ch * 32 + quad * 8);
    *(f32x4*)&ckv[4] = *(const f32x4*)(ckb + ch * 32 + quad * 8 + 4);

    // w = (2*adj) / (1 + exp2(|ck' - cm'|)), cadjs pre-scaled by log2(e)
    uint4v wfu;
#pragma unroll
    for (int p = 0; p < 4; ++p) {
      const unsigned u = au[p];
      const float a0 = __uint_as_float(u << 16);          // k even
      const float a1 = __uint_as_float(u & 0xFFFF0000u);  // k odd
      float d0 = ckv[2 * p] - cm;
      float e0 = __builtin_amdgcn_exp2f(fabsf(d0));
      float w0 = a0 * __builtin_amdgcn_rcpf(1.0f + e0);
      float d1 = ckv[2 * p + 1] - cm;
      float e1 = __builtin_amdgcn_exp2f(fabsf(d1));
      float w1 = a1 * __builtin_amdgcn_rcpf(1.0f + e1);
      // truncating bf16x2 pack: bytes [w0.b2, w0.b3, w1.b2, w1.b3]
      wfu[p] = __builtin_amdgcn_perm(__float_as_uint(w1), __float_as_uint(w0),
                                     0x07060302u);
    }
    const bf16x8 wf = __builtin_bit_cast(bf16x8, wfu);

    acc0 = __builtin_amdgcn_mfma_f32_16x16x32_bf16(fa0, wf, acc0, 0, 0, 0);
    acc1 = __builtin_amdgcn_mfma_f32_16x16x32_bf16(fa1, wf, acc1, 0, 0, 0);
  }

  // partials: part[kh][b][c][col]   (D layout: col=l15, row=quad*4+r)
  float* pp = part + ((size_t)(kh * B_DIM + b) * C_DIM) * N_DIM;
#pragma unroll
  for (int r = 0; r < 4; ++r) {
    const int c0 = quad * 4 + r;
    pp[(size_t)c0 * N_DIM + col] = acc0[r];
    pp[(size_t)(c0 + 16) * N_DIM + col] = acc1[r];
  }
}

// Epilogue: out = relu(para * (part[0] + part[1]))
__global__ __launch_bounds__(256) void epilogue_kernel(const float* __restrict__ part,
                                                       const float* __restrict__ para,
                                                       float* __restrict__ out) {
  const int t = blockIdx.x * 256 + threadIdx.x;    // float4 groups
  const int m4 = (t & 1023) * 4;
  const int bc = t >> 10;                          // b*32 + c
  const int c = bc & 31;
  const size_t base = (size_t)bc * N_DIM + m4;

  f32x4 s = {0.f, 0.f, 0.f, 0.f};
#pragma unroll
  for (int ks = 0; ks < KSPLIT; ++ks)
    s += *(const f32x4*)(part + (size_t)ks * (B_DIM * C_DIM * N_DIM) + base);

  const f32x4 p = *(const f32x4*)(para + (size_t)c * N_DIM + m4);
  f32x4 o;
#pragma unroll
  for (int i = 0; i < 4; ++i) o[i] = fmaxf(s[i] * p[i], 0.f);
  *(f32x4*)(out + base) = o;
}

extern "C" void kernel_launch(void* const* d_in, const int* in_sizes, int n_in,
                              void* d_out, int out_size, void* d_ws, size_t ws_size,
                              hipStream_t stream) {
  const float* x = (const float*)d_in[0];     // [8,32,64,64]
  const float* para = (const float*)d_in[1];  // [1,32,64,64]
  const float* adj = (const float*)d_in[2];   // [4096,4096]
  float* out = (float*)d_out;

  // ws: part (8 MB) | cadjs (128 KB) | feabT (2 MB) | adjt (32 MB)
  float* part = (float*)d_ws;
  float* cadjs = (float*)((char*)d_ws + (size_t)KSPLIT * B_DIM * C_DIM * N_DIM * 4);
  ushort* feabT = (ushort*)((char*)cadjs + (size_t)B_DIM * N_DIM * 4);
  ushort* adjt = (ushort*)((char*)feabT + (size_t)B_DIM * C_DIM * N_DIM * 2);

  prep_cadj<<<dim3(B_DIM * N_DIM / 256), dim3(256), 0, stream>>>(x, cadjs);
  prep_feab<<<dim3(B_DIM * C_DIM * (N_DIM / 16) / 256), dim3(256), 0, stream>>>(x, feabT);
  prep_adjT<<<dim3(N_DIM * (N_DIM / 16) / 256), dim3(256), 0, stream>>>(adj, adjt);
  gcn_stage1<<<dim3(N_DIM / 16, KSPLIT), dim3(512), 0, stream>>>(feabT, adjt, cadjs, part);
  epilogue_kernel<<<dim3(B_DIM * C_DIM * N_DIM / 4 / 256), dim3(256), 0, stream>>>(part, para, out);
}

// Round 14
// 175.005 us; speedup vs baseline: 1.0124x; 1.0124x over previous
//
#include <hip/hip_runtime.h>
#include <hip/hip_bf16.h>
#include <math.h>

#define B_DIM 8
#define C_DIM 32
#define N_DIM 4096
#define KSPLIT 2
#define KSL (N_DIM / KSPLIT)   // 2048 k per block
#define NCH (KSL / 32)         // 64 chunks

typedef short bf16x8 __attribute__((ext_vector_type(8)));   // 8 bf16 = 4 VGPRs
typedef float f32x4 __attribute__((ext_vector_type(4)));
typedef float f32x2 __attribute__((ext_vector_type(2)));
typedef unsigned int uint4v __attribute__((ext_vector_type(4)));
typedef unsigned short ushort8 __attribute__((ext_vector_type(8)));

__device__ __forceinline__ ushort f2bf_rne(float f) {
  unsigned u = __float_as_uint(f);
  u += 0x7FFF + ((u >> 16) & 1);
  return (ushort)(u >> 16);
}

// Prep A: per-node exponentials of the scaled channel-mean:
// E[b,n] = 2^(mean*log2e), I[b,n] = 2^(-mean*log2e).
// Hot loop then gets 2^(-|ck-cm|) = min(Ek*Im, Em*Ik): no exp2 per weight.
__global__ __launch_bounds__(256) void prep_e(const float* __restrict__ x,
                                              float* __restrict__ E,
                                              float* __restrict__ I) {
  int idx = blockIdx.x * 256 + threadIdx.x;   // 0 .. B*N-1
  int b = idx >> 12;
  int n = idx & (N_DIM - 1);
  const float* p = x + (size_t)b * C_DIM * N_DIM + n;
  float s = 0.f;
#pragma unroll
  for (int c = 0; c < C_DIM; ++c) s += p[(size_t)c * N_DIM];
  s *= (1.44269504f / C_DIM);
  E[idx] = __builtin_amdgcn_exp2f(s);
  I[idx] = __builtin_amdgcn_exp2f(-s);
}

// Prep B: feabT tiled bf16: feabT[((b*128 + n/32)*32 + c)*32 + n%32]
__global__ __launch_bounds__(256) void prep_feab(const float* __restrict__ x,
                                                 ushort* __restrict__ feabT) {
  int idx = blockIdx.x * 256 + threadIdx.x;   // 0 .. 8*32*256-1
  int g = idx & 255;           // n-group of 16
  int c = (idx >> 8) & 31;
  int b = idx >> 13;
  int n0 = g * 16;
  const float* p = x + ((size_t)(b * C_DIM + c)) * N_DIM + n0;
  ushort* q = feabT + ((size_t)(b * (N_DIM / 32) + (n0 >> 5)) * C_DIM + c) * 32 + (n0 & 31);
  ushort8 v0, v1;
#pragma unroll
  for (int j = 0; j < 8; ++j) v0[j] = f2bf_rne(p[j]);
#pragma unroll
  for (int j = 0; j < 8; ++j) v1[j] = f2bf_rne(p[8 + j]);
  *(ushort8*)q = v0;
  *(ushort8*)(q + 8) = v1;
}

// Stage 1: r12 skeleton (block = 8 waves = 8 batches, 16 cols, K-half, adj
// tile cooperatively staged through LDS, read once chip-wide) with 3 fixes:
//  - abuf rows padded to stride 17: the (quad*8+j) read pattern drops from
//    4-way (measured 4.2M conflict cycles) to free 2-way.
//  - double-buffered abuf -> ONE barrier per chunk instead of two.
//  - weight gen: t = min(Ek*Im, Em*Ik) replaces exp2(|d|); only rcp remains
//    transcendental. float2 form for v_pk_* codegen.
__global__ __launch_bounds__(512, 4) void gcn_stage1(
    const ushort* __restrict__ feabT, const float* __restrict__ adj,
    const float* __restrict__ E, const float* __restrict__ I,
    float* __restrict__ part) {
  __shared__ float abuf[2][32 * 17 + 4];   // padded; ~4.4 KB total

  const int tid = threadIdx.x;
  const int lane = tid & 63;
  const int b = tid >> 6;           // wave id = batch
  const int quad = lane >> 4;
  const int l15 = lane & 15;
  const int colgrp = blockIdx.x;    // 0..255
  const int kh = blockIdx.y;        // 0..1
  const int col = colgrp * 16 + l15;
  const int ksbase = kh * KSL;

  // staging address: thread tid covers (row tid>>4, col tid&15) of each tile
  const int srow = tid >> 4;
  const int scol = tid & 15;
  const float* agp = adj + (size_t)(ksbase + srow) * N_DIM + colgrp * 16 + scol;
  const int swaddr = srow * 17 + scol;

  const float* Eb = E + (size_t)b * N_DIM;
  const float* Ib = I + (size_t)b * N_DIM;
  const f32x2 Emv = {Eb[col], Eb[col]};
  const f32x2 Imv = {Ib[col], Ib[col]};
  const f32x2 onev = {1.0f, 1.0f};
  const ushort* fb = feabT + ((size_t)b * (N_DIM / 32) + (ksbase >> 5)) * (C_DIM * 32);

  f32x4 acc0 = {0.f, 0.f, 0.f, 0.f};   // channels 0-15
  f32x4 acc1 = {0.f, 0.f, 0.f, 0.f};   // channels 16-31

  // depth-3 staging rotation: rB = tile ch+1 (written at end of ch), rC = ch+2
  float rA = agp[0];
  float rB = agp[(size_t)32 * N_DIM];
  float rC = agp[(size_t)64 * N_DIM];
  abuf[0][swaddr] = 2.0f * rA;
  __syncthreads();

#pragma unroll 2
  for (int ch = 0; ch < NCH; ++ch) {
    const int cur = ch & 1;
    // far prefetch (tile ch+3), issued first; clamped index keeps it in-bounds
    const int chn = (ch + 3 < NCH) ? (ch + 3) : (NCH - 1);
    const float rD = agp[(size_t)chn * 32 * N_DIM];

    const ushort* tile = fb + (size_t)ch * (C_DIM * 32);
    const bf16x8 fa0 = *(const bf16x8*)(tile + l15 * 32 + quad * 8);
    const bf16x8 fa1 = *(const bf16x8*)(tile + (16 + l15) * 32 + quad * 8);

    const int koff = ch * 32 + quad * 8;
    f32x2 ekv[4], ikv[4];
    *(f32x4*)&ekv[0] = *(const f32x4*)(Eb + ksbase + koff);
    *(f32x4*)&ekv[2] = *(const f32x4*)(Eb + ksbase + koff + 4);
    *(f32x4*)&ikv[0] = *(const f32x4*)(Ib + ksbase + koff);
    *(f32x4*)&ikv[2] = *(const f32x4*)(Ib + ksbase + koff + 4);

    float a2v[8];
#pragma unroll
    for (int j = 0; j < 8; ++j) a2v[j] = abuf[cur][(quad * 8 + j) * 17 + l15];

    // w = (2*adj) * t * rcp(1+t),  t = 2^(-|ck'-cm'|) = min(Ek*Im, Em*Ik)
    uint4v wfu;
#pragma unroll
    for (int p = 0; p < 4; ++p) {
      f32x2 q = ekv[p] * Imv;
      f32x2 rr = ikv[p] * Emv;
      f32x2 t;
      t.x = fminf(q.x, rr.x);
      t.y = fminf(q.y, rr.y);
      f32x2 s1 = t + onev;
      f32x2 rc;
      rc.x = __builtin_amdgcn_rcpf(s1.x);
      rc.y = __builtin_amdgcn_rcpf(s1.y);
      f32x2 a2p = {a2v[2 * p], a2v[2 * p + 1]};
      f32x2 w = (a2p * t) * rc;
      // truncating bf16x2 pack: bytes [w.x.b2, w.x.b3, w.y.b2, w.y.b3]
      wfu[p] = __builtin_amdgcn_perm(__float_as_uint(w.y), __float_as_uint(w.x),
                                     0x07060302u);
    }
    const bf16x8 wf = __builtin_bit_cast(bf16x8, wfu);

    acc0 = __builtin_amdgcn_mfma_f32_16x16x32_bf16(fa0, wf, acc0, 0, 0, 0);
    acc1 = __builtin_amdgcn_mfma_f32_16x16x32_bf16(fa1, wf, acc1, 0, 0, 0);

    // stage tile ch+1 into the other buffer; ONE barrier per chunk
    if (ch + 1 < NCH) abuf[cur ^ 1][swaddr] = 2.0f * rB;
    rB = rC;
    rC = rD;
    __syncthreads();
  }

  // partials: part[kh][b][c][col]   (D layout: col=l15, row=quad*4+r)
  float* pp = part + ((size_t)(kh * B_DIM + b) * C_DIM) * N_DIM;
#pragma unroll
  for (int r = 0; r < 4; ++r) {
    const int c0 = quad * 4 + r;
    pp[(size_t)c0 * N_DIM + col] = acc0[r];
    pp[(size_t)(c0 + 16) * N_DIM + col] = acc1[r];
  }
}

// Epilogue: out = relu(para * (part[0] + part[1]))
__global__ __launch_bounds__(256) void epilogue_kernel(const float* __restrict__ part,
                                                       const float* __restrict__ para,
                                                       float* __restrict__ out) {
  const int t = blockIdx.x * 256 + threadIdx.x;    // float4 groups
  const int m4 = (t & 1023) * 4;
  const int bc = t >> 10;                          // b*32 + c
  const int c = bc & 31;
  const size_t base = (size_t)bc * N_DIM + m4;

  f32x4 s = {0.f, 0.f, 0.f, 0.f};
#pragma unroll
  for (int ks = 0; ks < KSPLIT; ++ks)
    s += *(const f32x4*)(part + (size_t)ks * (B_DIM * C_DIM * N_DIM) + base);

  const f32x4 p = *(const f32x4*)(para + (size_t)c * N_DIM + m4);
  f32x4 o;
#pragma unroll
  for (int i = 0; i < 4; ++i) o[i] = fmaxf(s[i] * p[i], 0.f);
  *(f32x4*)(out + base) = o;
}

extern "C" void kernel_launch(void* const* d_in, const int* in_sizes, int n_in,
                              void* d_out, int out_size, void* d_ws, size_t ws_size,
                              hipStream_t stream) {
  const float* x = (const float*)d_in[0];     // [8,32,64,64]
  const float* para = (const float*)d_in[1];  // [1,32,64,64]
  const float* adj = (const float*)d_in[2];   // [4096,4096]
  float* out = (float*)d_out;

  // ws: part (8 MB) | E (128 KB) | I (128 KB) | feabT (2 MB)
  float* part = (float*)d_ws;
  float* E = (float*)((char*)d_ws + (size_t)KSPLIT * B_DIM * C_DIM * N_DIM * 4);
  float* I = E + (size_t)B_DIM * N_DIM;
  ushort* feabT = (ushort*)(I + (size_t)B_DIM * N_DIM);

  prep_e<<<dim3(B_DIM * N_DIM / 256), dim3(256), 0, stream>>>(x, E, I);
  prep_feab<<<dim3(B_DIM * C_DIM * (N_DIM / 16) / 256), dim3(256), 0, stream>>>(x, feabT);
  gcn_stage1<<<dim3(N_DIM / 16, KSPLIT), dim3(512), 0, stream>>>(feabT, adj, E, I, part);
  epilogue_kernel<<<dim3(B_DIM * C_DIM * N_DIM / 4 / 256), dim3(256), 0, stream>>>(part, para, out);
}

// Round 15
// 146.408 us; speedup vs baseline: 1.2102x; 1.1953x over previous
//
#include <hip/hip_runtime.h>
#include <hip/hip_bf16.h>
#include <math.h>

#define B_DIM 8
#define C_DIM 32
#define N_DIM 4096
#define KSPLIT 2
#define KSL (N_DIM / KSPLIT)   // 2048 k per block
#define NCH (KSL / 32)         // 64 chunks

typedef short bf16x8 __attribute__((ext_vector_type(8)));   // 8 bf16 = 4 VGPRs
typedef float f32x4 __attribute__((ext_vector_type(4)));
typedef unsigned int uint4v __attribute__((ext_vector_type(4)));
typedef unsigned short ushort8 __attribute__((ext_vector_type(8)));

__device__ __forceinline__ ushort f2bf_rne(float f) {
  unsigned u = __float_as_uint(f);
  u += 0x7FFF + ((u >> 16) & 1);
  return (ushort)(u >> 16);
}

// Prep A: E[b,n] = exp(mean_c x[b,c,n]).  Hot loop uses the exact identity
// 2*sigmoid(-|ck-cm|) = 2*min(Ek,Em)/(Ek+Em): no transcendental per weight
// except rcp.
__global__ __launch_bounds__(256) void prep_e(const float* __restrict__ x,
                                              float* __restrict__ E) {
  int idx = blockIdx.x * 256 + threadIdx.x;   // 0 .. B*N-1
  int b = idx >> 12;
  int n = idx & (N_DIM - 1);
  const float* p = x + (size_t)b * C_DIM * N_DIM + n;
  float s = 0.f;
#pragma unroll
  for (int c = 0; c < C_DIM; ++c) s += p[(size_t)c * N_DIM];
  E[idx] = __builtin_amdgcn_exp2f(s * (1.44269504f / C_DIM));
}

// Prep B: feabT tiled bf16: feabT[((b*128 + n/32)*32 + c)*32 + n%32]
__global__ __launch_bounds__(256) void prep_feab(const float* __restrict__ x,
                                                 ushort* __restrict__ feabT) {
  int idx = blockIdx.x * 256 + threadIdx.x;   // 0 .. 8*32*256-1
  int g = idx & 255;           // n-group of 16
  int c = (idx >> 8) & 31;
  int b = idx >> 13;
  int n0 = g * 16;
  const float* p = x + ((size_t)(b * C_DIM + c)) * N_DIM + n0;
  ushort* q = feabT + ((size_t)(b * (N_DIM / 32) + (n0 >> 5)) * C_DIM + c) * 32 + (n0 & 31);
  ushort8 v0, v1;
#pragma unroll
  for (int j = 0; j < 8; ++j) v0[j] = f2bf_rne(p[j]);
#pragma unroll
  for (int j = 0; j < 8; ++j) v1[j] = f2bf_rne(p[8 + j]);
  *(ushort8*)q = v0;
  *(ushort8*)(q + 8) = v1;
}

// Stage 1: EXACT r12 skeleton (block = 8 waves = 8 batches, 16 cols, K-half,
// adj tile cooperatively staged through LDS with depth-2 register pipeline,
// 2 barriers/chunk, adj read once chip-wide) with two local fixes:
//  - abuf row stride 33: read bank = (row+l15)%32, distinct per quad -> free
//    (r12's stride 16 was 4-way: measured 4.2M conflict cycles).
//  - weight gen via the min-identity: w = a2 * min(Ek,Em) * rcp(Ek+Em);
//    saves the 8-cyc exp2 + the subtract per weight.
__global__ __launch_bounds__(512, 4) void gcn_stage1(
    const ushort* __restrict__ feabT, const float* __restrict__ adj,
    const float* __restrict__ E, float* __restrict__ part) {
  __shared__ float abuf[32 * 33 + 4];   // ~4.2 KB, row stride 33

  const int tid = threadIdx.x;
  const int lane = tid & 63;
  const int b = tid >> 6;           // wave id = batch
  const int quad = lane >> 4;
  const int l15 = lane & 15;
  const int colgrp = blockIdx.x;    // 0..255
  const int kh = blockIdx.y;        // 0..1
  const int col = colgrp * 16 + l15;
  const int ksbase = kh * KSL;

  // staging address: thread tid covers (row tid>>4, col tid&15) of each tile
  const float* agp = adj + (size_t)(ksbase + (tid >> 4)) * N_DIM + colgrp * 16 + (tid & 15);
  const int swaddr = (tid >> 4) * 33 + (tid & 15);

  const float* Eb = E + (size_t)b * N_DIM;
  const float Em = Eb[col];
  const float* ekb = Eb + ksbase;
  const ushort* fb = feabT + ((size_t)b * (N_DIM / 32) + (ksbase >> 5)) * (C_DIM * 32);

  f32x4 acc0 = {0.f, 0.f, 0.f, 0.f};   // channels 0-15
  f32x4 acc1 = {0.f, 0.f, 0.f, 0.f};   // channels 16-31

  // depth-2 adj staging pipeline (a_nxt = tile ch+1, a_nx2 = tile ch+2)
  float a_nxt = agp[0];
  float a_nx2 = agp[(size_t)32 * N_DIM];
  abuf[swaddr] = 2.0f * a_nxt;   // tile 0 into LDS
  a_nxt = a_nx2;
  __syncthreads();

  for (int ch = 0; ch < NCH; ++ch) {
    // issue tile ch+2's staging load now (~2 chunks of distance to its use)
    if (ch + 2 < NCH) a_nx2 = agp[(size_t)(ch + 2) * 32 * N_DIM];

    // fea fragments + E k-values for this wave's batch
    const ushort* tile = fb + (size_t)ch * (C_DIM * 32);
    const bf16x8 fa0 = *(const bf16x8*)(tile + l15 * 32 + quad * 8);
    const bf16x8 fa1 = *(const bf16x8*)(tile + (16 + l15) * 32 + quad * 8);
    float ekv[8];
    *(f32x4*)&ekv[0] = *(const f32x4*)(ekb + ch * 32 + quad * 8);
    *(f32x4*)&ekv[4] = *(const f32x4*)(ekb + ch * 32 + quad * 8 + 4);

    // adj fragment from LDS (shared by all 8 batches)
    float a2[8];
#pragma unroll
    for (int j = 0; j < 8; ++j) a2[j] = abuf[(quad * 8 + j) * 33 + l15];

    // w = (2*adj) * min(Ek,Em) * rcp(Ek+Em)   (exact: = 2*adj*sigmoid(-|d|)*2/2)
    uint4v wfu;
#pragma unroll
    for (int p = 0; p < 4; ++p) {
      const float e0 = ekv[2 * p];
      const float e1 = ekv[2 * p + 1];
      const float t0 = fminf(e0, Em);
      const float t1 = fminf(e1, Em);
      const float s0 = e0 + Em;
      const float s1 = e1 + Em;
      const float w0 = a2[2 * p] * t0 * __builtin_amdgcn_rcpf(s0);
      const float w1 = a2[2 * p + 1] * t1 * __builtin_amdgcn_rcpf(s1);
      // truncating bf16x2 pack: bytes [w0.b2, w0.b3, w1.b2, w1.b3]
      wfu[p] = __builtin_amdgcn_perm(__float_as_uint(w1), __float_as_uint(w0),
                                     0x07060302u);
    }
    const bf16x8 wf = __builtin_bit_cast(bf16x8, wfu);

    acc0 = __builtin_amdgcn_mfma_f32_16x16x32_bf16(fa0, wf, acc0, 0, 0, 0);
    acc1 = __builtin_amdgcn_mfma_f32_16x16x32_bf16(fa1, wf, acc1, 0, 0, 0);

    __syncthreads();   // all waves done reading abuf for tile ch
    if (ch + 1 < NCH) {
      abuf[swaddr] = 2.0f * a_nxt;   // value loaded >=1 full chunk ago
      a_nxt = a_nx2;
    }
    __syncthreads();   // staged writes visible to all waves
  }

  // partials: part[kh][b][c][col]   (D layout: col=l15, row=quad*4+r)
  float* pp = part + ((size_t)(kh * B_DIM + b) * C_DIM) * N_DIM;
#pragma unroll
  for (int r = 0; r < 4; ++r) {
    const int c0 = quad * 4 + r;
    pp[(size_t)c0 * N_DIM + col] = acc0[r];
    pp[(size_t)(c0 + 16) * N_DIM + col] = acc1[r];
  }
}

// Epilogue: out = relu(para * (part[0] + part[1]))
__global__ __launch_bounds__(256) void epilogue_kernel(const float* __restrict__ part,
                                                       const float* __restrict__ para,
                                                       float* __restrict__ out) {
  const int t = blockIdx.x * 256 + threadIdx.x;    // float4 groups
  const int m4 = (t & 1023) * 4;
  const int bc = t >> 10;                          // b*32 + c
  const int c = bc & 31;
  const size_t base = (size_t)bc * N_DIM + m4;

  f32x4 s = {0.f, 0.f, 0.f, 0.f};
#pragma unroll
  for (int ks = 0; ks < KSPLIT; ++ks)
    s += *(const f32x4*)(part + (size_t)ks * (B_DIM * C_DIM * N_DIM) + base);

  const f32x4 p = *(const f32x4*)(para + (size_t)c * N_DIM + m4);
  f32x4 o;
#pragma unroll
  for (int i = 0; i < 4; ++i) o[i] = fmaxf(s[i] * p[i], 0.f);
  *(f32x4*)(out + base) = o;
}

extern "C" void kernel_launch(void* const* d_in, const int* in_sizes, int n_in,
                              void* d_out, int out_size, void* d_ws, size_t ws_size,
                              hipStream_t stream) {
  const float* x = (const float*)d_in[0];     // [8,32,64,64]
  const float* para = (const float*)d_in[1];  // [1,32,64,64]
  const float* adj = (const float*)d_in[2];   // [4096,4096]
  float* out = (float*)d_out;

  // ws: part (8 MB) | E (128 KB) | feabT (2 MB)
  float* part = (float*)d_ws;
  float* E = (float*)((char*)d_ws + (size_t)KSPLIT * B_DIM * C_DIM * N_DIM * 4);
  ushort* feabT = (ushort*)(E + (size_t)B_DIM * N_DIM);

  prep_e<<<dim3(B_DIM * N_DIM / 256), dim3(256), 0, stream>>>(x, E);
  prep_feab<<<dim3(B_DIM * C_DIM * (N_DIM / 16) / 256), dim3(256), 0, stream>>>(x, feabT);
  gcn_stage1<<<dim3(N_DIM / 16, KSPLIT), dim3(512), 0, stream>>>(feabT, adj, E, part);
  epilogue_kernel<<<dim3(B_DIM * C_DIM * N_DIM / 4 / 256), dim3(256), 0, stream>>>(part, para, out);
}